// Round 12
// baseline (427.406 us; speedup 1.0000x reference)
//
#include <hip/hip_runtime.h>
#include <stdint.h>

typedef __bf16 bf16;
typedef unsigned int u32;
typedef __bf16 bf16x2 __attribute__((ext_vector_type(2)));
typedef __bf16 bf16x4 __attribute__((ext_vector_type(4)));
typedef __bf16 bf16x8 __attribute__((ext_vector_type(8)));
typedef float f32x4 __attribute__((ext_vector_type(4)));
typedef float f32x16 __attribute__((ext_vector_type(16)));

#define MFMA(a, b, c) __builtin_amdgcn_mfma_f32_16x16x32_bf16(a, b, c, 0, 0, 0)
#define MFMA32(a, b, c) __builtin_amdgcn_mfma_f32_32x32x16_bf16(a, b, c, 0, 0, 0)

// ---------------- prep kernels ----------------

__global__ void k_cast_x(const float* __restrict__ x, bf16* __restrict__ xb) {
    int i = (blockIdx.x * 256 + threadIdx.x) * 4;
    float4 v = *reinterpret_cast<const float4*>(x + i);
    bf16x4 o = { (bf16)v.x, (bf16)v.y, (bf16)v.z, (bf16)v.w };
    *reinterpret_cast<bf16x4*>(xb + i) = o;
}

__global__ void k_prep_w(const float* __restrict__ w0, const float* __restrict__ w1,
                         const float* __restrict__ w2, const float* __restrict__ w3,
                         bf16* __restrict__ o0, bf16* __restrict__ o1,
                         bf16* __restrict__ o2, bf16* __restrict__ o3) {
    __shared__ float t[64][65];
    const float* w; bf16* o;
    if (blockIdx.z == 0)      { w = w0; o = o0; }
    else if (blockIdx.z == 1) { w = w1; o = o1; }
    else if (blockIdx.z == 2) { w = w2; o = o2; }
    else                      { w = w3; o = o3; }
    int n0 = blockIdx.x * 64, k0 = blockIdx.y * 64;
    int tx = threadIdx.x & 63, ty = threadIdx.x >> 6;
    #pragma unroll
    for (int s = 0; s < 16; ++s) {
        int r = ty * 16 + s;
        t[r][tx] = w[(k0 + r) * 512 + n0 + tx];
    }
    __syncthreads();
    #pragma unroll
    for (int s = 0; s < 16; ++s) {
        int r = ty * 16 + s;
        o[(n0 + r) * 512 + k0 + tx] = (bf16)t[tx][r];
    }
}

__global__ void k_prep_er(const float* __restrict__ er, bf16* __restrict__ erB) {
    int i = blockIdx.x * 256 + threadIdx.x;
    int r = i >> 6;
    erB[i] = (r < 2048) ? (bf16)er[i] : (bf16)0.0f;
}

// ---------------- 64x64 GEMM tile core (unchanged) ----------------

__device__ __forceinline__ void gemm_tile_64x64(
    const bf16* __restrict__ A, const bf16* __restrict__ BT,
    int m0, int n0, bf16* la, bf16* lb, f32x4 (&acc)[4])
{
    const int tid = threadIdx.x;
    const int w = tid >> 6, lane = tid & 63;
    const int fm = lane & 15, fg = lane >> 4;
    const int srow = tid >> 2, sch = tid & 3;
    const int sph = sch ^ ((srow >> 1) & 3);
    for (int kt = 0; kt < 16; ++kt) {
        const int kb = kt * 32;
        __syncthreads();
        *reinterpret_cast<bf16x8*>(&la[srow * 32 + sph * 8]) =
            *reinterpret_cast<const bf16x8*>(&A[(m0 + srow) * 512 + kb + sch * 8]);
        *reinterpret_cast<bf16x8*>(&lb[srow * 32 + sph * 8]) =
            *reinterpret_cast<const bf16x8*>(&BT[(n0 + srow) * 512 + kb + sch * 8]);
        __syncthreads();
        const int ar = w * 16 + fm;
        bf16x8 af = *reinterpret_cast<const bf16x8*>(&la[ar * 32 + (fg ^ ((ar >> 1) & 3)) * 8]);
        #pragma unroll
        for (int c = 0; c < 4; ++c) {
            const int br = c * 16 + fm;
            bf16x8 bb = *reinterpret_cast<const bf16x8*>(&lb[br * 32 + (fg ^ ((br >> 1) & 3)) * 8]);
            acc[c] = MFMA(af, bb, acc[c]);
        }
    }
}

__global__ __launch_bounds__(256, 2) void k_gemm_qkv(
    const bf16* __restrict__ xb, const bf16* __restrict__ wqT,
    const bf16* __restrict__ wkT, const bf16* __restrict__ wvT,
    bf16* __restrict__ qo, bf16* __restrict__ ko, bf16* __restrict__ vTo)
{
    __shared__ bf16 la[64 * 32];
    __shared__ bf16 lb[64 * 32];
    const int m0 = blockIdx.x * 64, n0 = blockIdx.y * 64, z = blockIdx.z;
    const bf16* BT = (z == 0) ? wqT : (z == 1) ? wkT : wvT;
    f32x4 acc[4] = {};
    gemm_tile_64x64(xb, BT, m0, n0, la, lb, acc);
    const int w = threadIdx.x >> 6, lane = threadIdx.x & 63;
    const int fm = lane & 15, fg = lane >> 4;
    #pragma unroll
    for (int c = 0; c < 4; ++c)
        #pragma unroll
        for (int r = 0; r < 4; ++r) {
            const int m  = m0 + w * 16 + fg * 4 + r;
            const int nf = n0 + c * 16 + fm;
            const int b = m >> 11, tok = m & 2047;
            const int h = nf >> 6, d = nf & 63;
            const float v = acc[c][r];
            if (z == 0)      qo[((b * 8 + h) * 2048 + tok) * 64 + d] = (bf16)(v * 0.125f);
            else if (z == 1) ko[((b * 8 + h) * 2048 + tok) * 64 + d] = (bf16)v;
            else             vTo[((b * 8 + h) * 64 + d) * 2048 + tok] = (bf16)v;
        }
}

__global__ __launch_bounds__(256, 2) void k_gemm_out(
    const bf16* __restrict__ ao, const bf16* __restrict__ woT, float* __restrict__ out)
{
    __shared__ bf16 la[64 * 32];
    __shared__ bf16 lb[64 * 32];
    const int m0 = blockIdx.x * 64, n0 = blockIdx.y * 64;
    f32x4 acc[4] = {};
    gemm_tile_64x64(ao, woT, m0, n0, la, lb, acc);
    const int w = threadIdx.x >> 6, lane = threadIdx.x & 63;
    const int fm = lane & 15, fg = lane >> 4;
    #pragma unroll
    for (int c = 0; c < 4; ++c)
        #pragma unroll
        for (int r = 0; r < 4; ++r) {
            const int m  = m0 + w * 16 + fg * 4 + r;
            const int nf = n0 + c * 16 + fm;
            out[m * 512 + nf] = acc[c][r];
        }
}

// ---------------- swapped-operand 32x32 flash attention with relative bias ----------------
// 2 waves/block; wave w owns 32 q-rows [i0+32w, i0+32w+32). Swapped MFMA: lane holds a full
// q-row (col=lane&31): softmax in-lane + 1 shfl_xor(32); P repacked in-register (no LDS P).
// G bias via swapped mfma(Er,Q) -> wave-private LDS shear -> scalar reads (imm offsets).
__global__ __launch_bounds__(128, 2) void k_attn(
    const bf16* __restrict__ qg, const bf16* __restrict__ kg,
    const bf16* __restrict__ vg, const bf16* __restrict__ erB,
    bf16* __restrict__ ao)
{
    __shared__ bf16 lk[64 * 64];       // K tile [j][d], 8-chunk XOR swizzle
    __shared__ bf16 lv[64 * 64];       // V^T tile [d][j], 8-chunk XOR swizzle
    __shared__ bf16 gt[2][32 * 100];   // per-wave G [q][t 0..95], stride 100

    const int qt = 31 - blockIdx.x;    // heavy tiles first
    const int bh = blockIdx.y;
    const int i0 = qt * 64;
    const bf16* qp = qg + bh * 2048 * 64;
    const bf16* kp = kg + bh * 2048 * 64;
    const bf16* vp = vg + bh * 64 * 2048;

    const int tid = threadIdx.x;       // 0..127
    const int w = tid >> 6;
    const int lane = tid & 63;
    const int q = lane & 31;           // own q-row (strip-local); also A-row index for K/V frags
    const int h = lane >> 5;
    const int iw = i0 + 32 * w;
    const int iq = iw + q;             // own global q row
    const int qx = q & 7;              // swizzle key

    // Q B-fragments: bq[c] = Q[iq][16c+8h .. +7]
    bf16x8 bq[4];
    #pragma unroll
    for (int c = 0; c < 4; ++c)
        bq[c] = *reinterpret_cast<const bf16x8*>(&qp[iq * 64 + 16 * c + 8 * h]);

    // K/V staging prefetch (128 threads x 4 chunks x 16B per matrix)
    bf16x8 pk[4], pv[4];
    #pragma unroll
    for (int t = 0; t < 4; ++t) {
        const int cid = t * 128 + tid;
        const int row = cid >> 3, g = cid & 7;
        pk[t] = *reinterpret_cast<const bf16x8*>(&kp[row * 64 + g * 8]);
        pv[t] = *reinterpret_cast<const bf16x8*>(&vp[row * 2048 + g * 8]);
    }

    f32x16 oacc0 = {}, oacc1 = {};
    float mrow = -1e30f, lrow = 0.f;

    bf16* gtw = &gt[w][0];
    const int gbase = q * 100 + 31 - q + 4 * h;   // gather base (elements); +32s + (q4+8p) imm

    for (int j0 = 0; j0 <= i0; j0 += 64) {
        __syncthreads();
        #pragma unroll
        for (int t = 0; t < 4; ++t) {
            const int cid = t * 128 + tid;
            const int row = cid >> 3, g = cid & 7, ph = g ^ (row & 7);
            *reinterpret_cast<bf16x8*>(&lk[row * 64 + ph * 8]) = pk[t];
            *reinterpret_cast<bf16x8*>(&lv[row * 64 + ph * 8]) = pv[t];
        }
        __syncthreads();
        if (j0 + 64 <= i0) {
            const int j0n = j0 + 64;
            #pragma unroll
            for (int t = 0; t < 4; ++t) {
                const int cid = t * 128 + tid;
                const int row = cid >> 3, g = cid & 7;
                pk[t] = *reinterpret_cast<const bf16x8*>(&kp[(j0n + row) * 64 + g * 8]);
                pv[t] = *reinterpret_cast<const bf16x8*>(&vp[row * 2048 + j0n + g * 8]);
            }
        }

        // S^T = mfma(K, Q): sacc[s] holds S[k=32s+kr][q=lane&31] -> lane owns its q-row
        f32x16 sacc0 = {}, sacc1 = {};
        #pragma unroll
        for (int c = 0; c < 4; ++c) {
            bf16x8 ka = *reinterpret_cast<const bf16x8*>(&lk[(q)      * 64 + (((2*c+h) ^ qx) * 8)]);
            sacc0 = MFMA32(ka, bq[c], sacc0);
        }
        #pragma unroll
        for (int c = 0; c < 4; ++c) {
            bf16x8 ka = *reinterpret_cast<const bf16x8*>(&lk[(32 + q) * 64 + (((2*c+h) ^ qx) * 8)]);
            sacc1 = MFMA32(ka, bq[c], sacc1);
        }

        // G^T = mfma(ErBand, Q): band rows t = 0..95 (t = 31-m+jl), base tb
        const int tb = 2016 - iw + j0;
        #pragma unroll
        for (int u = 0; u < 3; ++u) {
            f32x16 gacc = {};
            #pragma unroll
            for (int c = 0; c < 4; ++c) {
                bf16x8 ea = *reinterpret_cast<const bf16x8*>(
                    &erB[(tb + 32 * u + q) * 64 + 16 * c + 8 * h]);
                gacc = MFMA32(ea, bq[c], gacc);
            }
            // store: lane holds G[t=32u+(r&3)+8(r>>2)+4h][q]; write bf16x4 per quad to gt[q][t]
            #pragma unroll
            for (int p = 0; p < 4; ++p) {
                bf16x4 gb = { (bf16)gacc[4*p], (bf16)gacc[4*p+1], (bf16)gacc[4*p+2], (bf16)gacc[4*p+3] };
                *reinterpret_cast<bf16x4*>(&gtw[q * 100 + 32 * u + 8 * p + 4 * h]) = gb;
            }
        }

        // bias add + causal mask + in-lane max
        const int dmax = iq - j0;
        float sv[2][16];
        #pragma unroll
        for (int r = 0; r < 16; ++r) {
            const int kr = (r & 3) + 8 * (r >> 2) + 4 * h;
            float v0 = sacc0[r] + (float)gtw[gbase + ((r & 3) + 8 * (r >> 2))];
            float v1 = sacc1[r] + (float)gtw[gbase + 32 + ((r & 3) + 8 * (r >> 2))];
            if (kr > dmax)       v0 = -3e38f;
            if (32 + kr > dmax)  v1 = -3e38f;
            sv[0][r] = v0; sv[1][r] = v1;
        }
        float mt[16];
        #pragma unroll
        for (int r = 0; r < 16; ++r) mt[r] = fmaxf(sv[0][r], sv[1][r]);
        #pragma unroll
        for (int d = 8; d > 0; d >>= 1)
            #pragma unroll
            for (int r = 0; r < 8; ++r) if (r < d) mt[r] = fmaxf(mt[r], mt[r + d]);
        float tm = fmaxf(mt[0], __shfl_xor(mt[0], 32, 64));
        const float mn = fmaxf(mrow, tm);
        const float fac = __expf(mrow - mn);
        mrow = mn;

        // p = exp(sv - mn); in-lane sum
        float rs[16];
        #pragma unroll
        for (int r = 0; r < 16; ++r) {
            sv[0][r] = __expf(sv[0][r] - mn);
            sv[1][r] = __expf(sv[1][r] - mn);
            rs[r] = sv[0][r] + sv[1][r];
        }
        #pragma unroll
        for (int d = 8; d > 0; d >>= 1)
            #pragma unroll
            for (int r = 0; r < 8; ++r) if (r < d) rs[r] += rs[r + d];
        const float rsum = rs[0] + __shfl_xor(rs[0], 32, 64);
        lrow = lrow * fac + rsum;
        #pragma unroll
        for (int r = 0; r < 16; ++r) { oacc0[r] *= fac; oacc1[r] *= fac; }

        // P repack in-register -> B-frags pb[c]: P^T[k=16c+8h..+7][q]
        bf16x8 pb[4];
        #pragma unroll
        for (int c = 0; c < 4; ++c) {
            const int s = c >> 1;
            const int pkq = 2 * (c & 1) + h;        // quad index this lane keeps
            const int psq = 2 * (c & 1) + (1 - h);  // quad index this lane sends
            const float* ps = sv[s];
            bf16x2 k0b = { (bf16)ps[4*pkq],   (bf16)ps[4*pkq+1] };
            bf16x2 k1b = { (bf16)ps[4*pkq+2], (bf16)ps[4*pkq+3] };
            bf16x2 s0b = { (bf16)ps[4*psq],   (bf16)ps[4*psq+1] };
            bf16x2 s1b = { (bf16)ps[4*psq+2], (bf16)ps[4*psq+3] };
            u32 keep0 = __builtin_bit_cast(u32, k0b);
            u32 keep1 = __builtin_bit_cast(u32, k1b);
            u32 send0 = __builtin_bit_cast(u32, s0b);
            u32 send1 = __builtin_bit_cast(u32, s1b);
            u32 recv0 = (u32)__shfl_xor((int)send0, 32, 64);
            u32 recv1 = (u32)__shfl_xor((int)send1, 32, 64);
            union { u32 u[4]; bf16x8 v; } asm_;
            asm_.u[0] = h ? recv0 : keep0;
            asm_.u[1] = h ? recv1 : keep1;
            asm_.u[2] = h ? keep0 : recv0;
            asm_.u[3] = h ? keep1 : recv1;
            pb[c] = asm_.v;
        }

        // O^T += mfma(V^T, P^T): oacc_e holds O[d=32e+dr][q]
        #pragma unroll
        for (int c = 0; c < 4; ++c) {
            bf16x8 va = *reinterpret_cast<const bf16x8*>(&lv[(q)      * 64 + (((2*c+h) ^ qx) * 8)]);
            oacc0 = MFMA32(va, pb[c], oacc0);
        }
        #pragma unroll
        for (int c = 0; c < 4; ++c) {
            bf16x8 va = *reinterpret_cast<const bf16x8*>(&lv[(32 + q) * 64 + (((2*c+h) ^ qx) * 8)]);
            oacc1 = MFMA32(va, pb[c], oacc1);
        }
    }

    // epilogue: lane owns row iq: ao[b][iq][hh*64 + d], d = 32e + 8p + 4h + 0..3
    const int b = bh >> 3, hh = bh & 7;
    const float inv = 1.0f / lrow;
    bf16* dst = ao + (b * 2048 + iq) * 512 + hh * 64;
    #pragma unroll
    for (int p = 0; p < 4; ++p) {
        bf16x4 o0 = { (bf16)(oacc0[4*p] * inv), (bf16)(oacc0[4*p+1] * inv),
                      (bf16)(oacc0[4*p+2] * inv), (bf16)(oacc0[4*p+3] * inv) };
        bf16x4 o1 = { (bf16)(oacc1[4*p] * inv), (bf16)(oacc1[4*p+1] * inv),
                      (bf16)(oacc1[4*p+2] * inv), (bf16)(oacc1[4*p+3] * inv) };
        *reinterpret_cast<bf16x4*>(&dst[8 * p + 4 * h])      = o0;
        *reinterpret_cast<bf16x4*>(&dst[32 + 8 * p + 4 * h]) = o1;
    }
}

// ---------------- host launcher ----------------

extern "C" void kernel_launch(void* const* d_in, const int* in_sizes, int n_in,
                              void* d_out, int out_size, void* d_ws, size_t ws_size,
                              hipStream_t stream) {
    (void)in_sizes; (void)n_in; (void)out_size; (void)ws_size;
    const float* x  = (const float*)d_in[0];
    const float* Wq = (const float*)d_in[1];
    const float* Wk = (const float*)d_in[2];
    const float* Wv = (const float*)d_in[3];
    const float* Wo = (const float*)d_in[4];
    const float* Er = (const float*)d_in[5];
    float* out = (float*)d_out;

    char* ws = (char*)d_ws;
    bf16* xb  = (bf16*)(ws);                  // 4096*512        = 4,194,304 B
    bf16* wqT = (bf16*)(ws + 4194304);
    bf16* wkT = (bf16*)(ws + 4718592);
    bf16* wvT = (bf16*)(ws + 5242880);
    bf16* woT = (bf16*)(ws + 5767168);
    bf16* erB = (bf16*)(ws + 6291456);        // 2176*64*2
    bf16* q   = (bf16*)(ws + 6569984);
    bf16* k   = (bf16*)(ws + 10764288);
    bf16* vT  = (bf16*)(ws + 14958592);
    bf16* ao  = (bf16*)(ws + 19152896);       // end 23,347,200 B

    k_cast_x<<<dim3(2048), dim3(256), 0, stream>>>(x, xb);
    k_prep_w<<<dim3(8, 8, 4), dim3(256), 0, stream>>>(Wq, Wk, Wv, Wo, wqT, wkT, wvT, woT);
    k_prep_er<<<dim3(544), dim3(256), 0, stream>>>(Er, erB);
    k_gemm_qkv<<<dim3(64, 8, 3), dim3(256), 0, stream>>>(xb, wqT, wkT, wvT, q, k, vT);
    k_attn<<<dim3(32, 16), dim3(128), 0, stream>>>(q, k, vT, erB, ao);
    k_gemm_out<<<dim3(64, 8), dim3(256), 0, stream>>>(ao, woT, out);
}